// Round 10
// baseline (429.966 us; speedup 1.0000x reference)
//
#include <hip/hip_runtime.h>
#include <hip/hip_bf16.h>

#define NROWS 65536
#define DDIM  2048
#define NEXP  8
#define THREADS 512
#define NBLOCKS 512
#define ROWS_PER_BLOCK (NROWS / NBLOCKS)        // 128
#define ROWS_PER_WAVE  (ROWS_PER_BLOCK / 8)     // 16 (8 waves/block)
#define PAIRS          (ROWS_PER_WAVE / 2)      // 8
#define KSTEPS         (DDIM / 256)             // 8

typedef float v4f __attribute__((ext_vector_type(4)));
typedef float v2f __attribute__((ext_vector_type(2)));

// Kernel A: gate scores -> masked softmax -> top1 prob. Writes (p, top1) to
// out[row*8 + {0,1}]; accumulates denom via LDS then 8 global atomics/block.
//
// Register-budget law (R1-R9): 512-thr + 64 KiB LDS -> 128-VGPR cap
// (2 blk/CU, 16 waves/CU — hard occupancy ceiling). Explicit load buffers
// of 32 regs spill (R5: 200 MB, R9: 105 MB scratch). Compiler unroll-4
// (R8, ~8-16 load regs) = 118.9 us clean. This round: KBATCH=2 via NAMED
// SCALARS (a0,b0,a1,b1 = 16 load regs, static indexing) — 4 loads issued
// back-to-back per macro-step, one notch more ILP than R8, inside the
// proven liveness envelope.
__global__ __launch_bounds__(THREADS) void gate_kernel(
    const float* __restrict__ x,       // (B, D)
    const int*   __restrict__ label,   // (B,)
    const float* __restrict__ w,       // (D, E) row-major
    const float* __restrict__ bgate,   // (E,)
    float* __restrict__ out,           // (B, E)
    float* __restrict__ denom)         // (E,) pre-zeroed
{
    __shared__ float wt[NEXP * DDIM];  // 64 KiB, wt[e*D + d]
    __shared__ float dsum[NEXP];
    __shared__ float sbg[NEXP];

    const int tid = threadIdx.x;
    if (tid < NEXP) { dsum[tid] = 0.0f; sbg[tid] = bgate[tid]; }

    // Stage w transposed into LDS (coalesced float4 reads, 8 per thread).
    for (int i = tid; i < (DDIM * NEXP) / 4; i += THREADS) {
        v4f v = *reinterpret_cast<const v4f*>(w + 4 * (size_t)i);
        const int d0 = i >> 1;
        const int e0 = (i & 1) * 4;
        wt[(e0 + 0) * DDIM + d0] = v.x;
        wt[(e0 + 1) * DDIM + d0] = v.y;
        wt[(e0 + 2) * DDIM + d0] = v.z;
        wt[(e0 + 3) * DDIM + d0] = v.w;
    }
    __syncthreads();

    const int wave = tid >> 6;
    const int lane = tid & 63;
    const int wrow = blockIdx.x * ROWS_PER_BLOCK + wave * ROWS_PER_WAVE;
    const float* xb = x + (size_t)wrow * DDIM + lane * 4;

    for (int p = 0; p < PAIRS; ++p) {
        const int roff0 = (p * 2) * DDIM;
        const int roff1 = roff0 + DDIM;

        float acc0[NEXP], acc1[NEXP];
#pragma unroll
        for (int e = 0; e < NEXP; ++e) { acc0[e] = 0.0f; acc1[e] = 0.0f; }

#pragma unroll
        for (int kk = 0; kk < KSTEPS / 2; ++kk) {
            const int k0 = 2 * kk, k1 = 2 * kk + 1;
            // Issue 4 loads (4 KB/wave) back-to-back, then consume.
            const v4f a0 = __builtin_nontemporal_load(
                reinterpret_cast<const v4f*>(xb + roff0 + k0 * 256));
            const v4f b0 = __builtin_nontemporal_load(
                reinterpret_cast<const v4f*>(xb + roff1 + k0 * 256));
            const v4f a1 = __builtin_nontemporal_load(
                reinterpret_cast<const v4f*>(xb + roff0 + k1 * 256));
            const v4f b1 = __builtin_nontemporal_load(
                reinterpret_cast<const v4f*>(xb + roff1 + k1 * 256));
#pragma unroll
            for (int e = 0; e < NEXP; ++e) {
                const v4f wv = *reinterpret_cast<const v4f*>(&wt[e * DDIM + k0 * 256 + lane * 4]);
                acc0[e] += a0.x * wv.x + a0.y * wv.y + a0.z * wv.z + a0.w * wv.w;
                acc1[e] += b0.x * wv.x + b0.y * wv.y + b0.z * wv.z + b0.w * wv.w;
            }
#pragma unroll
            for (int e = 0; e < NEXP; ++e) {
                const v4f wv = *reinterpret_cast<const v4f*>(&wt[e * DDIM + k1 * 256 + lane * 4]);
                acc0[e] += a1.x * wv.x + a1.y * wv.y + a1.z * wv.z + a1.w * wv.w;
                acc1[e] += b1.x * wv.x + b1.y * wv.y + b1.z * wv.z + b1.w * wv.w;
            }
        }

        // Per-row: butterfly reduce, then epilogue (keeps live set small).
#pragma unroll
        for (int r = 0; r < 2; ++r) {
            const int row = wrow + p * 2 + r;
            float s[NEXP];
#pragma unroll
            for (int e = 0; e < NEXP; ++e) {
                float v = r ? acc1[e] : acc0[e];
#pragma unroll
                for (int m = 32; m >= 1; m >>= 1)
                    v += __shfl_xor(v, m, 64);
                s[e] = v + sbg[e];
            }

            float mA = s[0]; int aA = 0;
            if (s[1] > mA) { mA = s[1]; aA = 1; }
            if (s[2] > mA) { mA = s[2]; aA = 2; }
            if (s[3] > mA) { mA = s[3]; aA = 3; }
            const float sumA = __expf(s[0] - mA) + __expf(s[1] - mA) +
                               __expf(s[2] - mA) + __expf(s[3] - mA);
            float mB = s[4]; int aB = 4;
            if (s[5] > mB) { mB = s[5]; aB = 5; }
            if (s[6] > mB) { mB = s[6]; aB = 6; }
            if (s[7] > mB) { mB = s[7]; aB = 7; }
            const float sumB = __expf(s[4] - mB) + __expf(s[5] - mB) +
                               __expf(s[6] - mB) + __expf(s[7] - mB);

            const int   lab = label[row];
            const int   arg = lab ? aB : aA;
            const float pv  = 1.0f / (lab ? sumB : sumA);

            if (lane == 0) {
                v2f o; o.x = pv; o.y = (float)arg;
                __builtin_nontemporal_store(
                    o, reinterpret_cast<v2f*>(out + (size_t)row * NEXP));
                atomicAdd(&dsum[arg], pv);
            }
        }
    }

    __syncthreads();
    if (tid < NEXP) atomicAdd(&denom[tid], dsum[tid]);
}

// Kernel B: out[row, e] = (e==top1) ? p/(denom[e]+eps)*B : 0
__global__ __launch_bounds__(256) void finalize_kernel(
    float* __restrict__ out, const float* __restrict__ denom)
{
    const int row = blockIdx.x * blockDim.x + threadIdx.x;
    if (row >= NROWS) return;
    const float p = out[(size_t)row * NEXP + 0];
    const int   a = (int)out[(size_t)row * NEXP + 1];
    const float val = p / (denom[a] + 1e-6f) * 65536.0f;

    float vals[NEXP];
#pragma unroll
    for (int e = 0; e < NEXP; ++e) vals[e] = (e == a) ? val : 0.0f;

    v4f o0; o0.x = vals[0]; o0.y = vals[1]; o0.z = vals[2]; o0.w = vals[3];
    v4f o1; o1.x = vals[4]; o1.y = vals[5]; o1.z = vals[6]; o1.w = vals[7];
    v4f* dst = reinterpret_cast<v4f*>(out + (size_t)row * NEXP);
    __builtin_nontemporal_store(o0, dst);
    __builtin_nontemporal_store(o1, dst + 1);
}

extern "C" void kernel_launch(void* const* d_in, const int* in_sizes, int n_in,
                              void* d_out, int out_size, void* d_ws, size_t ws_size,
                              hipStream_t stream) {
    const float* x     = (const float*)d_in[0];
    const int*   label = (const int*)d_in[1];
    const float* w     = (const float*)d_in[2];
    const float* bg    = (const float*)d_in[3];
    float* out   = (float*)d_out;
    float* denom = (float*)d_ws;   // 8 floats

    (void)hipMemsetAsync(denom, 0, NEXP * sizeof(float), stream);
    gate_kernel<<<NBLOCKS, THREADS, 0, stream>>>(x, label, w, bg, out, denom);
    finalize_kernel<<<NROWS / 256, 256, 0, stream>>>(out, denom);
}

// Round 11
// 126.130 us; speedup vs baseline: 3.4089x; 3.4089x over previous
//
#include <hip/hip_runtime.h>
#include <hip/hip_bf16.h>

#define NROWS 65536
#define DDIM  2048
#define NEXP  8
#define THREADS 512
#define NBLOCKS 512
#define ROWS_PER_BLOCK (NROWS / NBLOCKS)        // 128
#define ROWS_PER_WAVE  (ROWS_PER_BLOCK / 8)     // 16 (8 waves/block)
#define PAIRS          (ROWS_PER_WAVE / 2)      // 8
#define KSTEPS         (DDIM / 256)             // 8

typedef float v4f __attribute__((ext_vector_type(4)));
typedef float v2f __attribute__((ext_vector_type(2)));

// Kernel A: gate scores -> masked softmax -> top1 prob. Writes (p, top1) to
// out[row*8 + {0,1}]; accumulates denom via LDS then 8 global atomics/block.
//
// Laws learned (R1-R10):
//  - 512-thr + 64 KiB LDS -> 128-VGPR cap (2 blk/CU, 16 waves/CU hard cap).
//    1024-thr -> 64-reg cap -> spill (R2-R4).
//  - Manual load batching/prefetch (R5/R9/R10) -> compiler REMATERIALIZES
//    the side-effect-free loads at use (re-reads x, +0.5 GB FETCH) and/or
//    spills acc. Only compiler-scheduled unroll-4 (R8) stays clean: 118.9 us.
//  - This round's single variable vs R8: drop non-temporal on x loads
//    (nt bypasses L2; µbench ceilings were measured with normal loads).
__global__ __launch_bounds__(THREADS) void gate_kernel(
    const float* __restrict__ x,       // (B, D)
    const int*   __restrict__ label,   // (B,)
    const float* __restrict__ w,       // (D, E) row-major
    const float* __restrict__ bgate,   // (E,)
    float* __restrict__ out,           // (B, E)
    float* __restrict__ denom)         // (E,) pre-zeroed
{
    __shared__ float wt[NEXP * DDIM];  // 64 KiB, wt[e*D + d]
    __shared__ float dsum[NEXP];
    __shared__ float sbg[NEXP];

    const int tid = threadIdx.x;
    if (tid < NEXP) { dsum[tid] = 0.0f; sbg[tid] = bgate[tid]; }

    // Stage w transposed into LDS (coalesced float4 reads, 8 per thread).
    for (int i = tid; i < (DDIM * NEXP) / 4; i += THREADS) {
        v4f v = *reinterpret_cast<const v4f*>(w + 4 * (size_t)i);
        const int d0 = i >> 1;
        const int e0 = (i & 1) * 4;
        wt[(e0 + 0) * DDIM + d0] = v.x;
        wt[(e0 + 1) * DDIM + d0] = v.y;
        wt[(e0 + 2) * DDIM + d0] = v.z;
        wt[(e0 + 3) * DDIM + d0] = v.w;
    }
    __syncthreads();

    const int wave = tid >> 6;
    const int lane = tid & 63;
    const int wrow = blockIdx.x * ROWS_PER_BLOCK + wave * ROWS_PER_WAVE;
    const float* xb = x + (size_t)wrow * DDIM + lane * 4;

    for (int p = 0; p < PAIRS; ++p) {
        const int roff0 = (p * 2) * DDIM;
        const int roff1 = roff0 + DDIM;

        float acc0[NEXP], acc1[NEXP];
#pragma unroll
        for (int e = 0; e < NEXP; ++e) { acc0[e] = 0.0f; acc1[e] = 0.0f; }

#pragma unroll 4
        for (int k = 0; k < KSTEPS; ++k) {
            const v4f a = *reinterpret_cast<const v4f*>(xb + roff0 + k * 256);
            const v4f b = *reinterpret_cast<const v4f*>(xb + roff1 + k * 256);
#pragma unroll
            for (int e = 0; e < NEXP; ++e) {
                const v4f wv = *reinterpret_cast<const v4f*>(&wt[e * DDIM + k * 256 + lane * 4]);
                acc0[e] += a.x * wv.x + a.y * wv.y + a.z * wv.z + a.w * wv.w;
                acc1[e] += b.x * wv.x + b.y * wv.y + b.z * wv.z + b.w * wv.w;
            }
        }

        // Per-row: butterfly reduce, then epilogue (keeps live set small).
#pragma unroll
        for (int r = 0; r < 2; ++r) {
            const int row = wrow + p * 2 + r;
            float s[NEXP];
#pragma unroll
            for (int e = 0; e < NEXP; ++e) {
                float v = r ? acc1[e] : acc0[e];
#pragma unroll
                for (int m = 32; m >= 1; m >>= 1)
                    v += __shfl_xor(v, m, 64);
                s[e] = v + sbg[e];
            }

            float mA = s[0]; int aA = 0;
            if (s[1] > mA) { mA = s[1]; aA = 1; }
            if (s[2] > mA) { mA = s[2]; aA = 2; }
            if (s[3] > mA) { mA = s[3]; aA = 3; }
            const float sumA = __expf(s[0] - mA) + __expf(s[1] - mA) +
                               __expf(s[2] - mA) + __expf(s[3] - mA);
            float mB = s[4]; int aB = 4;
            if (s[5] > mB) { mB = s[5]; aB = 5; }
            if (s[6] > mB) { mB = s[6]; aB = 6; }
            if (s[7] > mB) { mB = s[7]; aB = 7; }
            const float sumB = __expf(s[4] - mB) + __expf(s[5] - mB) +
                               __expf(s[6] - mB) + __expf(s[7] - mB);

            const int   lab = label[row];
            const int   arg = lab ? aB : aA;
            const float pv  = 1.0f / (lab ? sumB : sumA);

            if (lane == 0) {
                v2f o; o.x = pv; o.y = (float)arg;
                *reinterpret_cast<v2f*>(out + (size_t)row * NEXP) = o;
                atomicAdd(&dsum[arg], pv);
            }
        }
    }

    __syncthreads();
    if (tid < NEXP) atomicAdd(&denom[tid], dsum[tid]);
}

// Kernel B: out[row, e] = (e==top1) ? p/(denom[e]+eps)*B : 0
__global__ __launch_bounds__(256) void finalize_kernel(
    float* __restrict__ out, const float* __restrict__ denom)
{
    const int row = blockIdx.x * blockDim.x + threadIdx.x;
    if (row >= NROWS) return;
    const float p = out[(size_t)row * NEXP + 0];
    const int   a = (int)out[(size_t)row * NEXP + 1];
    const float val = p / (denom[a] + 1e-6f) * 65536.0f;

    float vals[NEXP];
#pragma unroll
    for (int e = 0; e < NEXP; ++e) vals[e] = (e == a) ? val : 0.0f;

    v4f o0; o0.x = vals[0]; o0.y = vals[1]; o0.z = vals[2]; o0.w = vals[3];
    v4f o1; o1.x = vals[4]; o1.y = vals[5]; o1.z = vals[6]; o1.w = vals[7];
    v4f* dst = reinterpret_cast<v4f*>(out + (size_t)row * NEXP);
    __builtin_nontemporal_store(o0, dst);
    __builtin_nontemporal_store(o1, dst + 1);
}

extern "C" void kernel_launch(void* const* d_in, const int* in_sizes, int n_in,
                              void* d_out, int out_size, void* d_ws, size_t ws_size,
                              hipStream_t stream) {
    const float* x     = (const float*)d_in[0];
    const int*   label = (const int*)d_in[1];
    const float* w     = (const float*)d_in[2];
    const float* bg    = (const float*)d_in[3];
    float* out   = (float*)d_out;
    float* denom = (float*)d_ws;   // 8 floats

    (void)hipMemsetAsync(denom, 0, NEXP * sizeof(float), stream);
    gate_kernel<<<NBLOCKS, THREADS, 0, stream>>>(x, label, w, bg, out, denom);
    finalize_kernel<<<NROWS / 256, 256, 0, stream>>>(out, denom);
}

// Round 12
// 118.431 us; speedup vs baseline: 3.6305x; 1.0650x over previous
//
#include <hip/hip_runtime.h>
#include <hip/hip_bf16.h>

#define NROWS 65536
#define DDIM  2048
#define NEXP  8
#define THREADS 512
#define NBLOCKS 512
#define ROWS_PER_BLOCK (NROWS / NBLOCKS)        // 128
#define ROWS_PER_WAVE  (ROWS_PER_BLOCK / 8)     // 16 (8 waves/block)
#define PAIRS          (ROWS_PER_WAVE / 2)      // 8
#define KSTEPS         (DDIM / 256)             // 8

typedef float v4f __attribute__((ext_vector_type(4)));
typedef float v2f __attribute__((ext_vector_type(2)));

// FINAL (R8 configuration — best measured: 118.9 us total).
//
// Laws established over R1-R11 (counter-backed):
//  - 512-thr + 64 KiB LDS -> 128-VGPR cap (2 blk/CU, 16 waves/CU). This is
//    a hard quantization wall: <=64 regs doubles waves but forces spill
//    (R2-R4: 0.85-1.4 GB scratch); 128 regs fits the ~90-reg live set.
//  - Manual load batching/prefetch (R5/R9/R10) -> compiler rematerializes
//    side-effect-free loads at use (+0.5 GB FETCH) or spills acc. Only
//    compiler-scheduled unroll-4 stays clean.
//  - Non-temporal x loads: +6% (R8 118.9 vs R11 126.1 plain) — x is
//    stream-once; nt keeps it from evicting w/out from L2/LLC.
//  - Block count 512 vs 1024: neutral (R6 vs R11).
//  - Gate runs ~5.0 TB/s effective = ~80% of the 6.29 TB/s copy ceiling;
//    FETCH/WRITE at ideal; LDS conflicts 1.6%; remaining gap is read-stream
//    efficiency + the occupancy wall -> structural roofline.
__global__ __launch_bounds__(THREADS) void gate_kernel(
    const float* __restrict__ x,       // (B, D)
    const int*   __restrict__ label,   // (B,)
    const float* __restrict__ w,       // (D, E) row-major
    const float* __restrict__ bgate,   // (E,)
    float* __restrict__ out,           // (B, E)
    float* __restrict__ denom)         // (E,) pre-zeroed
{
    __shared__ float wt[NEXP * DDIM];  // 64 KiB, wt[e*D + d]
    __shared__ float dsum[NEXP];
    __shared__ float sbg[NEXP];

    const int tid = threadIdx.x;
    if (tid < NEXP) { dsum[tid] = 0.0f; sbg[tid] = bgate[tid]; }

    // Stage w transposed into LDS (coalesced float4 reads, 8 per thread).
    for (int i = tid; i < (DDIM * NEXP) / 4; i += THREADS) {
        v4f v = *reinterpret_cast<const v4f*>(w + 4 * (size_t)i);
        const int d0 = i >> 1;
        const int e0 = (i & 1) * 4;
        wt[(e0 + 0) * DDIM + d0] = v.x;
        wt[(e0 + 1) * DDIM + d0] = v.y;
        wt[(e0 + 2) * DDIM + d0] = v.z;
        wt[(e0 + 3) * DDIM + d0] = v.w;
    }
    __syncthreads();

    const int wave = tid >> 6;
    const int lane = tid & 63;
    const int wrow = blockIdx.x * ROWS_PER_BLOCK + wave * ROWS_PER_WAVE;
    const float* xb = x + (size_t)wrow * DDIM + lane * 4;

    for (int p = 0; p < PAIRS; ++p) {
        const int roff0 = (p * 2) * DDIM;
        const int roff1 = roff0 + DDIM;

        float acc0[NEXP], acc1[NEXP];
#pragma unroll
        for (int e = 0; e < NEXP; ++e) { acc0[e] = 0.0f; acc1[e] = 0.0f; }

#pragma unroll 4
        for (int k = 0; k < KSTEPS; ++k) {
            const v4f a = __builtin_nontemporal_load(
                reinterpret_cast<const v4f*>(xb + roff0 + k * 256));
            const v4f b = __builtin_nontemporal_load(
                reinterpret_cast<const v4f*>(xb + roff1 + k * 256));
#pragma unroll
            for (int e = 0; e < NEXP; ++e) {
                const v4f wv = *reinterpret_cast<const v4f*>(&wt[e * DDIM + k * 256 + lane * 4]);
                acc0[e] += a.x * wv.x + a.y * wv.y + a.z * wv.z + a.w * wv.w;
                acc1[e] += b.x * wv.x + b.y * wv.y + b.z * wv.z + b.w * wv.w;
            }
        }

        // Per-row: butterfly reduce, then epilogue (keeps live set small).
#pragma unroll
        for (int r = 0; r < 2; ++r) {
            const int row = wrow + p * 2 + r;
            float s[NEXP];
#pragma unroll
            for (int e = 0; e < NEXP; ++e) {
                float v = r ? acc1[e] : acc0[e];
#pragma unroll
                for (int m = 32; m >= 1; m >>= 1)
                    v += __shfl_xor(v, m, 64);
                s[e] = v + sbg[e];
            }

            float mA = s[0]; int aA = 0;
            if (s[1] > mA) { mA = s[1]; aA = 1; }
            if (s[2] > mA) { mA = s[2]; aA = 2; }
            if (s[3] > mA) { mA = s[3]; aA = 3; }
            const float sumA = __expf(s[0] - mA) + __expf(s[1] - mA) +
                               __expf(s[2] - mA) + __expf(s[3] - mA);
            float mB = s[4]; int aB = 4;
            if (s[5] > mB) { mB = s[5]; aB = 5; }
            if (s[6] > mB) { mB = s[6]; aB = 6; }
            if (s[7] > mB) { mB = s[7]; aB = 7; }
            const float sumB = __expf(s[4] - mB) + __expf(s[5] - mB) +
                               __expf(s[6] - mB) + __expf(s[7] - mB);

            const int   lab = label[row];
            const int   arg = lab ? aB : aA;
            const float pv  = 1.0f / (lab ? sumB : sumA);

            if (lane == 0) {
                v2f o; o.x = pv; o.y = (float)arg;
                __builtin_nontemporal_store(
                    o, reinterpret_cast<v2f*>(out + (size_t)row * NEXP));
                atomicAdd(&dsum[arg], pv);
            }
        }
    }

    __syncthreads();
    if (tid < NEXP) atomicAdd(&denom[tid], dsum[tid]);
}

// Kernel B: out[row, e] = (e==top1) ? p/(denom[e]+eps)*B : 0
__global__ __launch_bounds__(256) void finalize_kernel(
    float* __restrict__ out, const float* __restrict__ denom)
{
    const int row = blockIdx.x * blockDim.x + threadIdx.x;
    if (row >= NROWS) return;
    const float p = out[(size_t)row * NEXP + 0];
    const int   a = (int)out[(size_t)row * NEXP + 1];
    const float val = p / (denom[a] + 1e-6f) * 65536.0f;

    float vals[NEXP];
#pragma unroll
    for (int e = 0; e < NEXP; ++e) vals[e] = (e == a) ? val : 0.0f;

    v4f o0; o0.x = vals[0]; o0.y = vals[1]; o0.z = vals[2]; o0.w = vals[3];
    v4f o1; o1.x = vals[4]; o1.y = vals[5]; o1.z = vals[6]; o1.w = vals[7];
    v4f* dst = reinterpret_cast<v4f*>(out + (size_t)row * NEXP);
    __builtin_nontemporal_store(o0, dst);
    __builtin_nontemporal_store(o1, dst + 1);
}

extern "C" void kernel_launch(void* const* d_in, const int* in_sizes, int n_in,
                              void* d_out, int out_size, void* d_ws, size_t ws_size,
                              hipStream_t stream) {
    const float* x     = (const float*)d_in[0];
    const int*   label = (const int*)d_in[1];
    const float* w     = (const float*)d_in[2];
    const float* bg    = (const float*)d_in[3];
    float* out   = (float*)d_out;
    float* denom = (float*)d_ws;   // 8 floats

    (void)hipMemsetAsync(denom, 0, NEXP * sizeof(float), stream);
    gate_kernel<<<NBLOCKS, THREADS, 0, stream>>>(x, label, w, bg, out, denom);
    finalize_kernel<<<NROWS / 256, 256, 0, stream>>>(out, denom);
}